// Round 4
// baseline (933.555 us; speedup 1.0000x reference)
//
#include <hip/hip_runtime.h>
#include <cstdint>
#include <cstddef>

#define DEVI __device__ __forceinline__

constexpr int N_TOK = 4096, DIM = 1024, HID = 4096, NE = 8;
constexpr int NKR = N_TOK * 2;   // total routed rows (every token picks exactly 2 experts)

typedef __attribute__((ext_vector_type(8))) short short8;
typedef __attribute__((ext_vector_type(4))) float f32x4;

DEVI ushort f2bf(float f) {
  union { float f; uint32_t u; } v; v.f = f;
  uint32_t r = v.u + 0x7FFFu + ((v.u >> 16) & 1u);   // round-to-nearest-even
  return (ushort)(r >> 16);
}

DEVI float gelu_t(float x) {
  // tanh-approx GELU, matches jax.nn.gelu(approximate=True)
  float t = 0.7978845608028654f * (x + 0.044715f * x * x * x);
  t = fminf(fmaxf(t, -15.f), 15.f);
  float e = __expf(2.f * t);
  return 0.5f * x * (1.f + (e - 1.f) / (e + 1.f));
}

// Direct global->LDS DMA, 16B/lane. LDS dest is WAVE-UNIFORM base + lane*16
// (linear; no padding allowed). Global src is per-lane.
DEVI void gload_lds16(const ushort* g, ushort* l) {
  __builtin_amdgcn_global_load_lds(
      (const __attribute__((address_space(1))) void*)g,
      (__attribute__((address_space(3))) void*)l, 16, 0, 0);
}

// ---------------- x fp32 -> bf16 ----------------
__global__ void convert_x_kernel(const float* __restrict__ x, ushort* __restrict__ xbf) {
  int i = (blockIdx.x * 256 + threadIdx.x) * 4;
  float4 v = *(const float4*)(x + i);
  ushort4 o;
  o.x = f2bf(v.x); o.y = f2bf(v.y); o.z = f2bf(v.z); o.w = f2bf(v.w);
  *(ushort4*)(xbf + i) = o;
}

// ---------------- transpose [E][R][C] fp32 -> [E][C][R] bf16 ----------------
template<int R, int C>
__global__ void transpose_bf16(const float* __restrict__ src, ushort* __restrict__ dst) {
  __shared__ ushort t[64][68];          // 68: keep ushort4 rows 8B-aligned, break bank stride
  int e = blockIdx.z;
  const float* s = src + (size_t)e * R * C;
  ushort* d = dst + (size_t)e * R * C;
  int r0 = blockIdx.y * 64, c0 = blockIdx.x * 64;
  int lr = threadIdx.x >> 4;            // 0..15
  int lc = (threadIdx.x & 15) * 4;      // 0..60
#pragma unroll
  for (int i = 0; i < 4; ++i) {
    int r = lr + i * 16;
    float4 v = *(const float4*)(s + (size_t)(r0 + r) * C + c0 + lc);
    t[lc + 0][r] = f2bf(v.x);
    t[lc + 1][r] = f2bf(v.y);
    t[lc + 2][r] = f2bf(v.z);
    t[lc + 3][r] = f2bf(v.w);
  }
  __syncthreads();
#pragma unroll
  for (int i = 0; i < 4; ++i) {
    int c = lr + i * 16;                // output row = original column
    ushort4 o = *(const ushort4*)&t[c][lc];
    *(ushort4*)(d + (size_t)(c0 + c) * R + r0 + lc) = o;
  }
}

// ---------------- gating: logits -> softmax -> top2 (fp64 for ref-stable top-k) ----------------
__global__ void gate_kernel(const float* __restrict__ x, const float* __restrict__ gw,
                            const float* __restrict__ gb,
                            int* __restrict__ topi, float* __restrict__ topw,
                            int* __restrict__ counts) {
  int n = blockIdx.x;
  int lane = threadIdx.x;               // block = 1 wave = 64 lanes
  double p[NE];
#pragma unroll
  for (int e = 0; e < NE; ++e) p[e] = 0.0;
  const float* xr = x + (size_t)n * DIM;
  for (int d = lane; d < DIM; d += 64) {
    float xv = xr[d];
    const float* g = gw + (size_t)d * NE;
#pragma unroll
    for (int e = 0; e < NE; ++e) p[e] += (double)xv * (double)g[e];
  }
#pragma unroll
  for (int e = 0; e < NE; ++e) {
#pragma unroll
    for (int s = 32; s > 0; s >>= 1) p[e] += __shfl_down(p[e], s);
  }
  if (lane == 0) {
    double m = -1e300;
#pragma unroll
    for (int e = 0; e < NE; ++e) { p[e] += (double)gb[e]; if (p[e] > m) m = p[e]; }
    double s = 0.0, ex[NE];
#pragma unroll
    for (int e = 0; e < NE; ++e) { ex[e] = exp(p[e] - m); s += ex[e]; }
    double inv = 1.0 / s;
    int e0 = 0, e1 = 0; double v0 = -1.0, v1 = -1.0;
#pragma unroll
    for (int e = 0; e < NE; ++e) {
      double pe = ex[e] * inv;
      if (pe > v0)      { v1 = v0; e1 = e0; v0 = pe; e0 = e; }
      else if (pe > v1) { v1 = pe; e1 = e; }
    }
    topi[n * 2] = e0; topi[n * 2 + 1] = e1;
    topw[n * 2] = (float)v0; topw[n * 2 + 1] = (float)v1;
    atomicAdd(&counts[e0], 1);
    atomicAdd(&counts[e1], 1);
  }
}

__global__ void prefix_kernel(const int* __restrict__ counts, int* __restrict__ offs) {
  if (threadIdx.x == 0) {
    int s = 0;
    for (int e = 0; e < NE; ++e) { offs[e] = s; s += counts[e]; }
  }
}

__global__ void scatter_kernel(const int* __restrict__ topi, const float* __restrict__ topw,
                               const int* __restrict__ offs, int* __restrict__ fill,
                               int* __restrict__ tok, float* __restrict__ wgt) {
  int n = blockIdx.x * blockDim.x + threadIdx.x;
  if (n >= N_TOK) return;
#pragma unroll
  for (int k = 0; k < 2; ++k) {
    int e = topi[n * 2 + k];
    int pos = atomicAdd(&fill[e], 1);
    int g = offs[e] + pos;
    tok[g] = n;
    wgt[g] = topw[n * 2 + k];
  }
}

// ---------------- routed GEMM, 256x256 tile, BK=64, 8 waves, mfma 16x16x32 bf16 ------
// Structure change R4: 128^2/4-wave -> 256^2/8-wave (m248: grouped 256^2+2ph = 655 TF
// at K=1024). 4x MFMA work per barrier pair; 1 block/CU by design (128 KB LDS),
// 2 waves/SIMD self-overlap. 2-phase counted-vmcnt loop and T1 expert-slab swizzle
// retained. Layer 2 uses K-split (KS=2) to keep >=1 block/CU of real work; bias is
// applied by split 0 only, splits combine via the existing atomicAdd epilogue.
// FIRST: hbuf[g][h] = gelu( gather(x)[g] @ Wt[e]^T + b1 )        (K = DIM)
// !FIRST: out[tok[g]][d] += wgt[g] * ( hbuf[g] @ Wt[e]^T + b2 )  (K = HID)
template<int K, int NXT, int KS, bool FIRST>
__global__ __launch_bounds__(512, 2) void moe_gemm(
    const ushort* __restrict__ A,     // FIRST: xbf [N_TOK][DIM] ; else hbuf [NKR][HID]
    const ushort* __restrict__ B,     // FIRST: W1t [E][HID][DIM]; else W2t [E][DIM][HID]
    const float* __restrict__ bias,   // FIRST: b1 [E][HID]      ; else b2 [E][DIM]
    const int* __restrict__ tok, const float* __restrict__ wgt,
    const int* __restrict__ offs, const int* __restrict__ counts,
    ushort* __restrict__ hbuf, float* __restrict__ out)
{
  constexpr int NCOL = FIRST ? HID : DIM;
  constexpr int KB = K / KS;          // K handled per block
  constexpr int NK = KB / 64;         // K-steps per block (16 / 32; both even)
  constexpr int TSZ = 256 * 64;       // ushorts per LDS tile buffer (32 KB)
  // Linear [256][64] layout — REQUIRED by global_load_lds. Double-buffered: 128 KB.
  __shared__ ushort Asm[2 * TSZ];
  __shared__ ushort Bsm[2 * TSZ];

  // ---- T1 XCD-chunked swizzle: chunk == one expert (NE == 8 XCDs) ----
  // id order within chunk: yt fastest (B-panel reuse), then xt, then ksp.
  const int bid = blockIdx.x;
  const int e   = bid & 7;
  const int rem = bid >> 3;                 // 0 .. NXT*16*KS-1
  const int yt  = rem & 15;
  const int xt  = (rem >> 4) % NXT;
  const int ksp = rem / (16 * NXT);

  const int cnt = counts[e];
  const int mbase = yt * 256;
  if (mbase >= cnt) return;           // early-exit tiles beyond this expert's row count
  const int off = offs[e];
  const int nbase = xt * 256;
  int rv = cnt - mbase; if (rv > 256) rv = 256;

  const int tid = threadIdx.x;
  const int lane = tid & 63, wave = tid >> 6;   // 8 waves
  const int sr = tid >> 3;            // staging row 0..63 (+64 per pass)
  const int sc = (tid & 7) * 8;       // staging k-offset (8 bf16 = 16B)
  const int k0base = ksp * KB;

  // Per-lane global row pointers (gather for A). OOB rows clamp to a valid row:
  // their acc rows are garbage but the epilogue skips mm >= rv, and MFMA output
  // rows depend only on their own A row, so no contamination of valid rows.
  const ushort* arow[4];
  const ushort* brow[4];
  const ushort* Be = B + (size_t)e * ((size_t)HID * DIM) + (size_t)nbase * K;
#pragma unroll
  for (int i = 0; i < 4; ++i) {
    int r = sr + 64 * i;
    int rc = r < rv ? r : rv - 1;
    int g = off + mbase + rc;
    long t = FIRST ? (long)tok[g] : (long)g;
    arow[i] = A + t * (long)K + k0base + sc;
    brow[i] = Be + (size_t)r * K + k0base + sc; // B rows always valid (NCOL % 256 == 0)
  }

  f32x4 acc[8][4];
#pragma unroll
  for (int a = 0; a < 8; ++a)
#pragma unroll
    for (int b = 0; b < 4; ++b) acc[a][b] = (f32x4)0.f;

  const int quad = lane >> 4, lrow = lane & 15;
  const int WM = (wave >> 2) * 128;   // wave rows: 2 row-groups of 128
  const int WN = (wave & 3) * 64;     // wave cols: 4 col-groups of 64

  // 8 gload_lds per thread per tile. Pass i: wave w covers rows [i*64+w*8, +8);
  // lane l writes LDS base + l*16B = row (base + l>>3), shorts (l&7)*8.
  auto stage = [&](int buf, int k0) {
#pragma unroll
    for (int i = 0; i < 4; ++i) {
      gload_lds16(arow[i] + k0, &Asm[buf * TSZ + (i * 64 + wave * 8) * 64]);
      gload_lds16(brow[i] + k0, &Bsm[buf * TSZ + (i * 64 + wave * 8) * 64]);
    }
  };
  auto compute = [&](int buf) {
#pragma unroll
    for (int ks = 0; ks < 2; ++ks) {
      short8 af[8], bf[4];
#pragma unroll
      for (int mt = 0; mt < 8; ++mt)
        af[mt] = *(const short8*)&Asm[buf * TSZ + (WM + mt * 16 + lrow) * 64 + ks * 32 + quad * 8];
#pragma unroll
      for (int nt = 0; nt < 4; ++nt)
        bf[nt] = *(const short8*)&Bsm[buf * TSZ + (WN + nt * 16 + lrow) * 64 + ks * 32 + quad * 8];
#pragma unroll
      for (int mt = 0; mt < 8; ++mt)
#pragma unroll
        for (int nt = 0; nt < 4; ++nt)
          acc[mt][nt] = __builtin_amdgcn_mfma_f32_16x16x32_bf16(af[mt], bf[nt], acc[mt][nt], 0, 0, 0);
    }
  };

  stage(0, 0);
  int cur = 0;
  for (int t = 0; t + 1 < NK; ++t) {
    stage(cur ^ 1, (t + 1) * 64);                      // prefetch next tile
    asm volatile("s_waitcnt vmcnt(8)" ::: "memory");   // current tile's loads done
    __builtin_amdgcn_s_barrier();                      // all waves' loads done
    __builtin_amdgcn_sched_barrier(0);                 // pin ds_reads below (rule 18)
    compute(cur);
    __builtin_amdgcn_sched_barrier(0);                 // pin reads above the barrier
    __builtin_amdgcn_s_barrier();                      // all reads of buf done before
    cur ^= 1;                                          //   next iter overwrites it
  }
  __syncthreads();                    // epilogue: drain last tile (vmcnt(0)+barrier)
  compute(cur);

  // epilogue: C/D layout col = lane&15, row = quad*4 + reg
  if (FIRST) {
#pragma unroll
    for (int mt = 0; mt < 8; ++mt) {
#pragma unroll
      for (int i = 0; i < 4; ++i) {
        int mm = WM + mt * 16 + quad * 4 + i;
        if (mm >= rv) continue;
        size_t g = (size_t)(off + mbase + mm);
#pragma unroll
        for (int nt = 0; nt < 4; ++nt) {
          int col = nbase + WN + nt * 16 + lrow;
          float v = gelu_t(acc[mt][nt][i] + bias[e * NCOL + col]);
          hbuf[g * HID + col] = f2bf(v);
        }
      }
    }
  } else {
#pragma unroll
    for (int mt = 0; mt < 8; ++mt) {
#pragma unroll
      for (int i = 0; i < 4; ++i) {
        int mm = WM + mt * 16 + quad * 4 + i;
        if (mm >= rv) continue;
        int g = off + mbase + mm;
        long t = tok[g];
        float w = wgt[g];
#pragma unroll
        for (int nt = 0; nt < 4; ++nt) {
          int col = nbase + WN + nt * 16 + lrow;
          float bb = (ksp == 0) ? bias[e * NCOL + col] : 0.f;   // bias once per output
          float v = w * (acc[mt][nt][i] + bb);
          atomicAdd(out + t * DIM + col, v);
        }
      }
    }
  }
}

extern "C" void kernel_launch(void* const* d_in, const int* in_sizes, int n_in,
                              void* d_out, int out_size, void* d_ws, size_t ws_size,
                              hipStream_t stream) {
  const float* x  = (const float*)d_in[0];
  const float* gw = (const float*)d_in[1];
  const float* gb = (const float*)d_in[2];
  const float* W1 = (const float*)d_in[3];
  const float* b1 = (const float*)d_in[4];
  const float* W2 = (const float*)d_in[5];
  const float* b2 = (const float*)d_in[6];
  float* out = (float*)d_out;

  // ---- workspace layout (small buffers first, big buffers after) ----
  char* ws = (char*)d_ws;
  size_t o = 0;
  auto alloc = [&](size_t b) { char* p = ws + o; o = (o + b + 255) & ~(size_t)255; return p; };
  int*    tok  = (int*)alloc(NKR * 4);
  float*  wgt  = (float*)alloc(NKR * 4);
  int*    topi = (int*)alloc(N_TOK * 2 * 4);
  float*  topw = (float*)alloc(N_TOK * 2 * 4);
  int*    counts = (int*)alloc(2 * NE * 4);
  int*    fill = counts + NE;
  int*    offs = (int*)alloc(NE * 4);
  ushort* xbf  = (ushort*)alloc((size_t)N_TOK * DIM * 2);        //   8 MB
  ushort* hbuf = (ushort*)alloc((size_t)NKR * HID * 2);          //  64 MB
  ushort* Wt   = (ushort*)alloc((size_t)NE * HID * DIM * 2);     //  64 MB (shared: W1t then W2t)
  size_t need = o;

  // out must be zeroed before the atomic-combine epilogue (out_size = element count).
  hipMemsetAsync(out, 0, (size_t)out_size * sizeof(float), stream);
  if (ws_size < need) return;   // guard: never write past d_ws (clean absmax failure)

  hipMemsetAsync(counts, 0, 2 * NE * 4, stream);

  convert_x_kernel<<<(N_TOK * DIM / 4) / 256, 256, 0, stream>>>(x, xbf);
  gate_kernel<<<N_TOK, 64, 0, stream>>>(x, gw, gb, topi, topw, counts);
  prefix_kernel<<<1, 64, 0, stream>>>(counts, offs);
  scatter_kernel<<<(N_TOK + 255) / 256, 256, 0, stream>>>(topi, topw, offs, fill, tok, wgt);

  // ---- expert MLP layer 1: Wt <- W1^T, hbuf = gelu(gather(x) @ W1 + b1) ----
  // grid: 16 yt (worst-case cnt=4096) x 16 xt x 8 experts, 512 threads
  transpose_bf16<DIM, HID><<<dim3(HID / 64, DIM / 64, NE), 256, 0, stream>>>(W1, Wt);
  moe_gemm<DIM, HID / 256, 1, true ><<<dim3(16 * (HID / 256) * 1 * NE), 512, 0, stream>>>(
      xbf, Wt, b1, tok, wgt, offs, counts, hbuf, out);

  // ---- expert MLP layer 2: Wt <- W2^T (reuse), out += wgt * (hbuf @ W2 + b2) ----
  // K-split 2: grid 16 yt x 4 xt x 2 ks x 8 experts
  transpose_bf16<HID, DIM><<<dim3(DIM / 64, HID / 64, NE), 256, 0, stream>>>(W2, Wt);
  moe_gemm<HID, DIM / 256, 2, false><<<dim3(16 * (DIM / 256) * 2 * NE), 512, 0, stream>>>(
      hbuf, Wt, b2, tok, wgt, offs, counts, hbuf, out);
}

// Round 5
// 869.088 us; speedup vs baseline: 1.0742x; 1.0742x over previous
//
#include <hip/hip_runtime.h>
#include <cstdint>
#include <cstddef>

#define DEVI __device__ __forceinline__

constexpr int N_TOK = 4096, DIM = 1024, HID = 4096, NE = 8;
constexpr int NKR = N_TOK * 2;   // total routed rows (every token picks exactly 2 experts)

typedef __attribute__((ext_vector_type(8))) short short8;
typedef __attribute__((ext_vector_type(4))) float f32x4;

DEVI ushort f2bf(float f) {
  union { float f; uint32_t u; } v; v.f = f;
  uint32_t r = v.u + 0x7FFFu + ((v.u >> 16) & 1u);   // round-to-nearest-even
  return (ushort)(r >> 16);
}

DEVI float gelu_t(float x) {
  // tanh-approx GELU, matches jax.nn.gelu(approximate=True)
  float t = 0.7978845608028654f * (x + 0.044715f * x * x * x);
  t = fminf(fmaxf(t, -15.f), 15.f);
  float e = __expf(2.f * t);
  return 0.5f * x * (1.f + (e - 1.f) / (e + 1.f));
}

// Direct global->LDS DMA, 16B/lane. LDS dest is WAVE-UNIFORM base + lane*16
// (linear; no padding allowed). Global src is per-lane.
DEVI void gload_lds16(const ushort* g, ushort* l) {
  __builtin_amdgcn_global_load_lds(
      (const __attribute__((address_space(1))) void*)g,
      (__attribute__((address_space(3))) void*)l, 16, 0, 0);
}

// ---------------- x fp32 -> bf16 ----------------
__global__ void convert_x_kernel(const float* __restrict__ x, ushort* __restrict__ xbf) {
  int i = (blockIdx.x * 256 + threadIdx.x) * 4;
  float4 v = *(const float4*)(x + i);
  ushort4 o;
  o.x = f2bf(v.x); o.y = f2bf(v.y); o.z = f2bf(v.z); o.w = f2bf(v.w);
  *(ushort4*)(xbf + i) = o;
}

// ---------------- transpose [E][R][C] fp32 -> [E][C][R] bf16 ----------------
template<int R, int C>
__global__ void transpose_bf16(const float* __restrict__ src, ushort* __restrict__ dst) {
  __shared__ ushort t[64][68];          // 68: keep ushort4 rows 8B-aligned, break bank stride
  int e = blockIdx.z;
  const float* s = src + (size_t)e * R * C;
  ushort* d = dst + (size_t)e * R * C;
  int r0 = blockIdx.y * 64, c0 = blockIdx.x * 64;
  int lr = threadIdx.x >> 4;            // 0..15
  int lc = (threadIdx.x & 15) * 4;      // 0..60
#pragma unroll
  for (int i = 0; i < 4; ++i) {
    int r = lr + i * 16;
    float4 v = *(const float4*)(s + (size_t)(r0 + r) * C + c0 + lc);
    t[lc + 0][r] = f2bf(v.x);
    t[lc + 1][r] = f2bf(v.y);
    t[lc + 2][r] = f2bf(v.z);
    t[lc + 3][r] = f2bf(v.w);
  }
  __syncthreads();
#pragma unroll
  for (int i = 0; i < 4; ++i) {
    int c = lr + i * 16;                // output row = original column
    ushort4 o = *(const ushort4*)&t[c][lc];
    *(ushort4*)(d + (size_t)(c0 + c) * R + r0 + lc) = o;
  }
}

// ---------------- gating: logits -> softmax -> top2 (fp64 for ref-stable top-k) ----------------
__global__ void gate_kernel(const float* __restrict__ x, const float* __restrict__ gw,
                            const float* __restrict__ gb,
                            int* __restrict__ topi, float* __restrict__ topw,
                            int* __restrict__ counts) {
  int n = blockIdx.x;
  int lane = threadIdx.x;               // block = 1 wave = 64 lanes
  double p[NE];
#pragma unroll
  for (int e = 0; e < NE; ++e) p[e] = 0.0;
  const float* xr = x + (size_t)n * DIM;
  for (int d = lane; d < DIM; d += 64) {
    float xv = xr[d];
    const float* g = gw + (size_t)d * NE;
#pragma unroll
    for (int e = 0; e < NE; ++e) p[e] += (double)xv * (double)g[e];
  }
#pragma unroll
  for (int e = 0; e < NE; ++e) {
#pragma unroll
    for (int s = 32; s > 0; s >>= 1) p[e] += __shfl_down(p[e], s);
  }
  if (lane == 0) {
    double m = -1e300;
#pragma unroll
    for (int e = 0; e < NE; ++e) { p[e] += (double)gb[e]; if (p[e] > m) m = p[e]; }
    double s = 0.0, ex[NE];
#pragma unroll
    for (int e = 0; e < NE; ++e) { ex[e] = exp(p[e] - m); s += ex[e]; }
    double inv = 1.0 / s;
    int e0 = 0, e1 = 0; double v0 = -1.0, v1 = -1.0;
#pragma unroll
    for (int e = 0; e < NE; ++e) {
      double pe = ex[e] * inv;
      if (pe > v0)      { v1 = v0; e1 = e0; v0 = pe; e0 = e; }
      else if (pe > v1) { v1 = pe; e1 = e; }
    }
    topi[n * 2] = e0; topi[n * 2 + 1] = e1;
    topw[n * 2] = (float)v0; topw[n * 2 + 1] = (float)v1;
    atomicAdd(&counts[e0], 1);
    atomicAdd(&counts[e1], 1);
  }
}

__global__ void prefix_kernel(const int* __restrict__ counts, int* __restrict__ offs) {
  if (threadIdx.x == 0) {
    int s = 0;
    for (int e = 0; e < NE; ++e) { offs[e] = s; s += counts[e]; }
  }
}

__global__ void scatter_kernel(const int* __restrict__ topi, const float* __restrict__ topw,
                               const int* __restrict__ offs, int* __restrict__ fill,
                               int* __restrict__ tok, float* __restrict__ wgt) {
  int n = blockIdx.x * blockDim.x + threadIdx.x;
  if (n >= N_TOK) return;
#pragma unroll
  for (int k = 0; k < 2; ++k) {
    int e = topi[n * 2 + k];
    int pos = atomicAdd(&fill[e], 1);
    int g = offs[e] + pos;
    tok[g] = n;
    wgt[g] = topw[n * 2 + k];
  }
}

// ---------------- routed GEMM, 256x256 tile, BK=64, 8 waves, 8-phase schedule -------
// R5: T3+T4 (4 phases/K-tile, counted vmcnt(2) at tile boundary only) + T2 (LDS XOR
// swizzle via PRE-SWIZZLED global source: lane slot s of row r loads global slot
// s^(r&7); reader reads LDS slot (ks*4+quad)^(lrow&7) -> every ds_read_b128 is
// bank-balanced) + T5 (setprio around MFMA clusters). T1 expert-chunk swizzle and
// KS split kept from R4.
//
// Swizzle proof (one element): lane 45 of wave 1, chunk 0: writes LDS row 13
// slot 5 <- global slot 5^5=0 (rows: r&7 == lane>>3; slots: lane&7). Reader of
// logical slot 0, row 13 (lrow=13, quad=0, ks=0) reads LDS slot 0^(13&7)=5. OK.
//
// Pipeline invariant: entering tile t's P0, this wave has <=8 outstanding VMEM
// (tile t's chunks, staged during t-1's phases). P0 issues chunk0 of t+1 (2),
// then vmcnt(2): waits t's 8 (older) done, keeps t+1's 2 in flight. P1..P3 issue
// chunks 1..3 of t+1. Never drains to 0 except the final tile (vmcnt(0)).
// Buffer safety: t+1 stages into buf (t+1)&1, which held t-1's data; all reads
// of t-1 retired before t's P0 barrier (each phase's reads consumed pre-barrier).
//
// FIRST: hbuf[g][h] = gelu( gather(x)[g] @ Wt[e]^T + b1 )        (K = DIM)
// !FIRST: out[tok[g]][d] += wgt[g] * ( hbuf[g] @ Wt[e]^T + b2 )  (K = HID)
template<int K, int NXT, int KS, bool FIRST>
__global__ __launch_bounds__(512, 2) void moe_gemm(
    const ushort* __restrict__ A,     // FIRST: xbf [N_TOK][DIM] ; else hbuf [NKR][HID]
    const ushort* __restrict__ B,     // FIRST: W1t [E][HID][DIM]; else W2t [E][DIM][HID]
    const float* __restrict__ bias,   // FIRST: b1 [E][HID]      ; else b2 [E][DIM]
    const int* __restrict__ tok, const float* __restrict__ wgt,
    const int* __restrict__ offs, const int* __restrict__ counts,
    ushort* __restrict__ hbuf, float* __restrict__ out)
{
  constexpr int NCOL = FIRST ? HID : DIM;
  constexpr int KB = K / KS;          // K handled per block
  constexpr int NK = KB / 64;         // K-tiles per block (16 / 32)
  constexpr int TSZB = 256 * 64 * 2;  // bytes per LDS tile buffer (32 KB)
  __shared__ ushort Asm[2 * 256 * 64];   // 64 KB, double-buffered A tiles
  __shared__ ushort Bsm[2 * 256 * 64];   // 64 KB, double-buffered B tiles

  // ---- T1 XCD-chunked swizzle: chunk == one expert (NE == 8 XCDs) ----
  const int bid = blockIdx.x;
  const int e   = bid & 7;
  const int rem = bid >> 3;
  const int yt  = rem & 15;
  const int xt  = (rem >> 4) % NXT;
  const int ksp = rem / (16 * NXT);

  const int cnt = counts[e];
  const int mbase = yt * 256;
  if (mbase >= cnt) return;           // early-exit tiles beyond this expert's row count
  const int off = offs[e];
  const int nbase = xt * 256;
  int rv = cnt - mbase; if (rv > 256) rv = 256;

  const int tid = threadIdx.x;
  const int lane = tid & 63, wave = tid >> 6;   // 8 waves
  const int sr = tid >> 3;            // staging row 0..63 (+64 per chunk)
  // T2 pre-swizzled source slot: slot (lane&7) of row (r: r&7 == lane>>3)
  // sources global slot (lane&7)^(lane>>3).  16B slots, units = ushort.
  const int scs = (((lane & 7) ^ (lane >> 3)) * 8);
  const int k0base = ksp * KB;

  // Per-lane global row pointers (gather for A). OOB rows clamp to a valid row:
  // their acc rows are garbage but the epilogue skips mm >= rv.
  const ushort* arow[4];
  const ushort* brow[4];
  const ushort* Be = B + (size_t)e * ((size_t)HID * DIM) + (size_t)nbase * K;
#pragma unroll
  for (int i = 0; i < 4; ++i) {
    int r = sr + 64 * i;
    int rc = r < rv ? r : rv - 1;
    int g = off + mbase + rc;
    long t = FIRST ? (long)tok[g] : (long)g;
    arow[i] = A + t * (long)K + k0base + scs;
    brow[i] = Be + (size_t)r * K + k0base + scs; // B rows always valid (NCOL % 256 == 0)
  }

  f32x4 acc[8][4];
#pragma unroll
  for (int a = 0; a < 8; ++a)
#pragma unroll
    for (int b = 0; b < 4; ++b) acc[a][b] = (f32x4)0.f;

  const int quad = lane >> 4, lrow = lane & 15;
  const int WM = (wave >> 2) * 128;   // wave rows: 2 row-groups of 128
  const int WN = (wave & 3) * 64;     // wave cols: 4 col-groups of 64

  // ds_read addressing (byte offsets), reader-side T2 un-swizzle baked into xo.
  int rowA[8], rowB[4], xo[2];
#pragma unroll
  for (int mt = 0; mt < 8; ++mt) rowA[mt] = (WM + mt * 16 + lrow) * 128;
#pragma unroll
  for (int nt = 0; nt < 4; ++nt) rowB[nt] = (WN + nt * 16 + lrow) * 128;
#pragma unroll
  for (int ks = 0; ks < 2; ++ks) xo[ks] = ((ks * 4 + quad) ^ (lane & 7)) * 16;

#define STAGE_CHUNK(P)                                                         \
  { gload_lds16(arow[P] + kn, (ushort*)(An + ((P) * 64 + wave * 8) * 128));    \
    gload_lds16(brow[P] + kn, (ushort*)(Bn + ((P) * 64 + wave * 8) * 128)); }
#define LD_AF(MH, KSX)                                                         \
  { _Pragma("unroll") for (int j = 0; j < 4; ++j)                              \
      af[j] = *(const short8*)(A0 + rowA[(MH) * 4 + j] + xo[KSX]); }
#define LD_BF(KSX)                                                             \
  { _Pragma("unroll") for (int j = 0; j < 4; ++j)                              \
      bfr[j] = *(const short8*)(B0 + rowB[j] + xo[KSX]); }
#define MFMA16(MH)                                                             \
  { _Pragma("unroll") for (int j = 0; j < 4; ++j)                              \
      _Pragma("unroll") for (int nt = 0; nt < 4; ++nt)                         \
        acc[(MH) * 4 + j][nt] = __builtin_amdgcn_mfma_f32_16x16x32_bf16(       \
            af[j], bfr[nt], acc[(MH) * 4 + j][nt], 0, 0, 0); }

  // ---- prologue: stage all 4 chunks of tile 0 into buf 0 ----
  {
    char* An = (char*)Asm; char* Bn = (char*)Bsm; const int kn = 0;
    STAGE_CHUNK(0); STAGE_CHUNK(1); STAGE_CHUNK(2); STAGE_CHUNK(3);
  }

  for (int t = 0; t < NK; ++t) {
    const int cb = t & 1;
    const char* A0 = (const char*)Asm + cb * TSZB;
    const char* B0 = (const char*)Bsm + cb * TSZB;
    char* An = (char*)Asm + (cb ^ 1) * TSZB;
    char* Bn = (char*)Bsm + (cb ^ 1) * TSZB;
    const int kn = (t + 1) * 64;
    const bool more = (t + 1 < NK);     // block-uniform
    short8 af[4], bfr[4];

    // ---- P0 (tile boundary): publish tile t, keep next-tile loads in flight ----
    if (more) {
      STAGE_CHUNK(0);
      asm volatile("s_waitcnt vmcnt(2)" ::: "memory");
    } else {
      asm volatile("s_waitcnt vmcnt(0)" ::: "memory");
    }
    __builtin_amdgcn_s_barrier();
    __builtin_amdgcn_sched_barrier(0);
    LD_AF(0, 0); LD_BF(0);
    __builtin_amdgcn_s_setprio(1); MFMA16(0); __builtin_amdgcn_s_setprio(0);
    __builtin_amdgcn_sched_barrier(0);
    __builtin_amdgcn_s_barrier();

    // ---- P1 ----
    LD_AF(1, 0);
    if (more) STAGE_CHUNK(1);
    __builtin_amdgcn_s_barrier();
    __builtin_amdgcn_sched_barrier(0);
    __builtin_amdgcn_s_setprio(1); MFMA16(1); __builtin_amdgcn_s_setprio(0);
    __builtin_amdgcn_sched_barrier(0);
    __builtin_amdgcn_s_barrier();

    // ---- P2 ----
    LD_AF(0, 1); LD_BF(1);
    if (more) STAGE_CHUNK(2);
    __builtin_amdgcn_s_barrier();
    __builtin_amdgcn_sched_barrier(0);
    __builtin_amdgcn_s_setprio(1); MFMA16(0); __builtin_amdgcn_s_setprio(0);
    __builtin_amdgcn_sched_barrier(0);
    __builtin_amdgcn_s_barrier();

    // ---- P3 ----
    LD_AF(1, 1);
    if (more) STAGE_CHUNK(3);
    __builtin_amdgcn_s_barrier();
    __builtin_amdgcn_sched_barrier(0);
    __builtin_amdgcn_s_setprio(1); MFMA16(1); __builtin_amdgcn_s_setprio(0);
    __builtin_amdgcn_sched_barrier(0);
    __builtin_amdgcn_s_barrier();
  }

#undef STAGE_CHUNK
#undef LD_AF
#undef LD_BF
#undef MFMA16

  // epilogue: C/D layout col = lane&15, row = quad*4 + reg
  if (FIRST) {
#pragma unroll
    for (int mt = 0; mt < 8; ++mt) {
#pragma unroll
      for (int i = 0; i < 4; ++i) {
        int mm = WM + mt * 16 + quad * 4 + i;
        if (mm >= rv) continue;
        size_t g = (size_t)(off + mbase + mm);
#pragma unroll
        for (int nt = 0; nt < 4; ++nt) {
          int col = nbase + WN + nt * 16 + lrow;
          float v = gelu_t(acc[mt][nt][i] + bias[e * NCOL + col]);
          hbuf[g * HID + col] = f2bf(v);
        }
      }
    }
  } else {
#pragma unroll
    for (int mt = 0; mt < 8; ++mt) {
#pragma unroll
      for (int i = 0; i < 4; ++i) {
        int mm = WM + mt * 16 + quad * 4 + i;
        if (mm >= rv) continue;
        int g = off + mbase + mm;
        long t = tok[g];
        float w = wgt[g];
#pragma unroll
        for (int nt = 0; nt < 4; ++nt) {
          int col = nbase + WN + nt * 16 + lrow;
          float bb = (ksp == 0) ? bias[e * NCOL + col] : 0.f;   // bias once per output
          float v = w * (acc[mt][nt][i] + bb);
          atomicAdd(out + t * DIM + col, v);
        }
      }
    }
  }
}

extern "C" void kernel_launch(void* const* d_in, const int* in_sizes, int n_in,
                              void* d_out, int out_size, void* d_ws, size_t ws_size,
                              hipStream_t stream) {
  const float* x  = (const float*)d_in[0];
  const float* gw = (const float*)d_in[1];
  const float* gb = (const float*)d_in[2];
  const float* W1 = (const float*)d_in[3];
  const float* b1 = (const float*)d_in[4];
  const float* W2 = (const float*)d_in[5];
  const float* b2 = (const float*)d_in[6];
  float* out = (float*)d_out;

  // ---- workspace layout (small buffers first, big buffers after) ----
  char* ws = (char*)d_ws;
  size_t o = 0;
  auto alloc = [&](size_t b) { char* p = ws + o; o = (o + b + 255) & ~(size_t)255; return p; };
  int*    tok  = (int*)alloc(NKR * 4);
  float*  wgt  = (float*)alloc(NKR * 4);
  int*    topi = (int*)alloc(N_TOK * 2 * 4);
  float*  topw = (float*)alloc(N_TOK * 2 * 4);
  int*    counts = (int*)alloc(2 * NE * 4);
  int*    fill = counts + NE;
  int*    offs = (int*)alloc(NE * 4);
  ushort* xbf  = (ushort*)alloc((size_t)N_TOK * DIM * 2);        //   8 MB
  ushort* hbuf = (ushort*)alloc((size_t)NKR * HID * 2);          //  64 MB
  ushort* Wt   = (ushort*)alloc((size_t)NE * HID * DIM * 2);     //  64 MB (shared: W1t then W2t)
  size_t need = o;

  // out must be zeroed before the atomic-combine epilogue (out_size = element count).
  hipMemsetAsync(out, 0, (size_t)out_size * sizeof(float), stream);
  if (ws_size < need) return;   // guard: never write past d_ws (clean absmax failure)

  hipMemsetAsync(counts, 0, 2 * NE * 4, stream);

  convert_x_kernel<<<(N_TOK * DIM / 4) / 256, 256, 0, stream>>>(x, xbf);
  gate_kernel<<<N_TOK, 64, 0, stream>>>(x, gw, gb, topi, topw, counts);
  prefix_kernel<<<1, 64, 0, stream>>>(counts, offs);
  scatter_kernel<<<(N_TOK + 255) / 256, 256, 0, stream>>>(topi, topw, offs, fill, tok, wgt);

  // ---- expert MLP layer 1: Wt <- W1^T, hbuf = gelu(gather(x) @ W1 + b1) ----
  transpose_bf16<DIM, HID><<<dim3(HID / 64, DIM / 64, NE), 256, 0, stream>>>(W1, Wt);
  moe_gemm<DIM, HID / 256, 1, true ><<<dim3(16 * (HID / 256) * 1 * NE), 512, 0, stream>>>(
      xbf, Wt, b1, tok, wgt, offs, counts, hbuf, out);

  // ---- expert MLP layer 2: Wt <- W2^T (reuse), out += wgt * (hbuf @ W2 + b2) ----
  transpose_bf16<HID, DIM><<<dim3(DIM / 64, HID / 64, NE), 256, 0, stream>>>(W2, Wt);
  moe_gemm<HID, DIM / 256, 2, false><<<dim3(16 * (DIM / 256) * 2 * NE), 512, 0, stream>>>(
      hbuf, Wt, b2, tok, wgt, offs, counts, hbuf, out);
}